// Round 14
// baseline (523.715 us; speedup 1.0000x reference)
//
#include <hip/hip_runtime.h>
#include <hip/hip_bf16.h>
#include <hip/hip_fp16.h>

// Problem constants (reference: OUT=11008, IN=4096, B=2, S=2048)
#define K_DIM 4096
#define N_DIM 11008
#define M_DIM 4096  // B*S

typedef _Float16 f16x8 __attribute__((ext_vector_type(8)));
typedef float f32x4 __attribute__((ext_vector_type(4)));

typedef const __attribute__((address_space(1))) void* gas_cptr;
typedef __attribute__((address_space(3))) void* las_ptr;

__device__ __forceinline__ void gload_lds16(const void* g, void* l) {
  __builtin_amdgcn_global_load_lds((gas_cptr)g, (las_ptr)l, 16, 0, 0);
}

// ---------------------------------------------------------------------------
// Dequant via per-row LUT (r9, proven): 256 curve values per row in LDS,
// then vectorized gather. 16x fewer powf -> memory-bound.
// ---------------------------------------------------------------------------
__global__ __launch_bounds__(256) void dequant_kernel(
    const int* __restrict__ mag, const int* __restrict__ sgn,
    const float* __restrict__ scales, const float* __restrict__ alphas,
    const float* __restrict__ powers, const float* __restrict__ divisors,
    _Float16* __restrict__ Wh) {
  __shared__ float tbl[256];
  const int o = blockIdx.x;   // row
  const int t = threadIdx.x;
  {
    float sc = scales[o];
    float al = alphas[o];
    float p = powers[o];
    float idv = 1.0f / divisors[o];
    float xn = (float)t * idv;
    float pw = __powf(xn, p);  // t==0 -> 0
    tbl[t] = sc * (al * xn + (1.0f - al) * pw);
  }
  __syncthreads();

  const size_t base = (size_t)o * K_DIM + (size_t)t * 16;
  const int4* mp = (const int4*)(mag + base);
  const int4* sp = (const int4*)(sgn + base);
  int4 m0 = mp[0], m1 = mp[1], m2 = mp[2], m3 = mp[3];
  int4 s0 = sp[0], s1 = sp[1], s2 = sp[2], s3 = sp[3];

  int mi[16] = {m0.x, m0.y, m0.z, m0.w, m1.x, m1.y, m1.z, m1.w,
                m2.x, m2.y, m2.z, m2.w, m3.x, m3.y, m3.z, m3.w};
  int si[16] = {s0.x, s0.y, s0.z, s0.w, s1.x, s1.y, s1.z, s1.w,
                s2.x, s2.y, s2.z, s2.w, s3.x, s3.y, s3.z, s3.w};

  f16x8 oa, ob;
#pragma unroll
  for (int e = 0; e < 8; ++e) oa[e] = (_Float16)((float)si[e] * tbl[mi[e]]);
#pragma unroll
  for (int e = 0; e < 8; ++e) ob[e] = (_Float16)((float)si[8 + e] * tbl[mi[8 + e]]);
  *(f16x8*)&Wh[base] = oa;
  *(f16x8*)&Wh[base + 8] = ob;
}

// ---------------------------------------------------------------------------
// x (fp32) -> fp16
// ---------------------------------------------------------------------------
__global__ __launch_bounds__(256) void xconv_kernel(const float* __restrict__ x,
                                                    _Float16* __restrict__ xh) {
  int v = blockIdx.x * 256 + threadIdx.x;
  int base = v * 8;
  float4 a = *(const float4*)(x + base);
  float4 b = *(const float4*)(x + base + 4);
  f16x8 o;
  o[0] = (_Float16)a.x; o[1] = (_Float16)a.y;
  o[2] = (_Float16)a.z; o[3] = (_Float16)a.w;
  o[4] = (_Float16)b.x; o[5] = (_Float16)b.y;
  o[6] = (_Float16)b.z; o[7] = (_Float16)b.w;
  *(f16x8*)&xh[base] = o;
}

// ---------------------------------------------------------------------------
// 256x256 GEMM_BT, BK=32, 4 WAVES of 128x128 each (2x2), 16x16x32 f16 MFMA.
// LDS-TRAFFIC play (r12 design; r13 fixed the staging-offset bug): at 8 waves
// the CU does 6 duplicated operand-units of ds_read per tile -> LDS pipe ~
// MFMA pipe, serialized (sum) -> 44% MfmaUtil across 6 schedule variants.
// At 4 waves of 128x128: duplication 4 units (-33%), MFMA:b128 = 4 -> per
// K32-tile/CU: LDS ~770cy < MFMA ~1240cy.  acc 8x8xf32x4 = 256 regs ->
// ~350 VGPR/wave, 1 wave/SIMD (launch_bounds(256,1), 512-reg budget).
// *** r13 BUGFIX: row = 32 f16 (64B), so sweep j (rows j*64..j*64+63) is at
// LDS f16-offset j*2048 (j*64*32), NOT j*4096.  Max offset now
// 3*2048+3*512+511 = 8191 (exactly fills the 8192-f16 region). ***
// Macro-schedule = r11's proven 3-buffer counted-vmcnt rotation: stage t+2,
// VMC(8) drains t+1, never 0 mid-loop.  Ledger re-audited: prologue stages
// t0,t1, VMC(8) drains t0; iter t stages t+2 (16 outstanding), VMC(8) drains
// t+1; reads of buf[t%3] were drained at t-1's VMC(8), published by t-1's
// BAR; buf[(t+2)%3]'s readers lgkm-retired before t-1's closing BAR.
// Swizzle (T2, r11-proven at BK=32): colbyte ^= ((row>>1)&3)<<4; sweep rows
// j*64+sr keep the same bits ((j*64+sr)>>1)&3 == (sr>>1)&3.
// ---------------------------------------------------------------------------
#define BM 256
#define BN 256
#define BK 32
#define NT (K_DIM / BK)   // 128
#define NBN (N_DIM / BN)  // 43
#define NBM (M_DIM / BM)  // 16

#define BAR() __builtin_amdgcn_s_barrier()
#define LGKM0()                                              \
  asm volatile("s_waitcnt lgkmcnt(0)" ::: "memory");         \
  __builtin_amdgcn_sched_barrier(0)
#define VMC(N) asm volatile("s_waitcnt vmcnt(" #N ")" ::: "memory")

// stage one K32-tile (A 256x32 = 16KB + B 256x32 = 16KB) = 8 gloads/thread.
// sweep j covers rows j*64..j*64+63 at LDS f16-offset j*2048 (r13 fix);
// thread (wave,lane) supplies row wave*16 + lane/4, col chunk (lane&3)*16B.
#define STAGE(buf_, ga_, gb_)                                            \
  _Pragma("unroll") for (int j = 0; j < 4; ++j) {                        \
    gload_lds16((ga_) + (size_t)(j * 64) * K_DIM,                        \
                &lds[buf_][0][j * 2048 + wave * 512]);                   \
    gload_lds16((gb_) + (size_t)(j * 64) * K_DIM,                        \
                &lds[buf_][1][j * 2048 + wave * 512]);                   \
  }

// 16 b128 reads: 8 A-frags (rows wm*128+f*16+frow) + 8 B-frags
#define RD_AB(buf_)                                                      \
  do {                                                                   \
    _Pragma("unroll") for (int f = 0; f < 8; ++f)                        \
        af[f] = *(const f16x8*)&lds[buf_][0][aoff + f * 512];            \
    _Pragma("unroll") for (int f = 0; f < 8; ++f)                        \
        bf[f] = *(const f16x8*)&lds[buf_][1][boff + f * 512];            \
  } while (0)

#define MFMA64()                                                         \
  do {                                                                   \
    __builtin_amdgcn_s_setprio(1);                                       \
    _Pragma("unroll") for (int i = 0; i < 8; ++i)                        \
        _Pragma("unroll") for (int j = 0; j < 8; ++j)                    \
            acc[i][j] = __builtin_amdgcn_mfma_f32_16x16x32_f16(          \
                af[i], bf[j], acc[i][j], 0, 0, 0);                       \
    __builtin_amdgcn_s_setprio(0);                                       \
  } while (0)

#define BODY(cur_, stg_, tn_)                                            \
  do {                                                                   \
    RD_AB(cur_);                                                         \
    STAGE(stg_, gA + (size_t)(tn_)*BK, gB + (size_t)(tn_)*BK);           \
    VMC(8);                                                              \
    BAR();                                                               \
    LGKM0();                                                             \
    MFMA64();                                                            \
    BAR();                                                               \
  } while (0)

__global__ __launch_bounds__(256, 1) void gemm_kernel(
    const _Float16* __restrict__ A, const _Float16* __restrict__ Bt,
    float* __restrict__ C) {
  __shared__ _Float16 lds[3][2][8192];  // 3 bufs x {A,B} x 16KB = 96 KiB

  const int tid = threadIdx.x;
  const int lane = tid & 63;
  const int wave = tid >> 6;  // 0..3
  const int wm = wave >> 1;   // 0..1
  const int wn = wave & 1;    // 0..1

  // XCD-aware swizzle (T1), bn-fastest (r4-proven): 688 = 8 XCDs x 86
  const int bid = blockIdx.x;
  const int g = (bid & 7) * 86 + (bid >> 3);
  const int bm = g / NBN;
  const int bn = g - bm * NBN;
  const size_t row0 = (size_t)bm * BM;
  const size_t col0 = (size_t)bn * BN;

  // staging addressing (T2 pre-swizzled source), rows 0..63 per sweep
  const int sr = tid >> 2;               // 0..63
  const int pcb = (tid & 3) * 16;
  const int cb = pcb ^ (((sr >> 1) & 3) << 4);
  const _Float16* gA = A + (row0 + sr) * (size_t)K_DIM + cb / 2;
  const _Float16* gB = Bt + (col0 + sr) * (size_t)K_DIM + cb / 2;

  // fragment read addressing (16x16x32: row=lane&15, kgrp=lane>>4; r11-proven)
  const int frow = lane & 15;
  const int fpcb = 16 * ((lane >> 4) ^ ((lane >> 1) & 3));
  const int aoff = (wm * 128 + frow) * 32 + fpcb / 2;  // + f*512
  const int boff = (wn * 128 + frow) * 32 + fpcb / 2;  // + f*512

  f32x4 acc[8][8];
#pragma unroll
  for (int m = 0; m < 8; ++m)
#pragma unroll
    for (int n = 0; n < 8; ++n) acc[m][n] = (f32x4)0.0f;

  f16x8 af[8], bf[8];

  // prologue: stage tiles 0,1; drain tile 0 (VMC(8) leaves t1 in flight)
  STAGE(0, gA, gB);
  STAGE(1, gA + BK, gB + BK);
  VMC(8);
  BAR();

  // main loop: t = 0..125 (126 = 3*42), buffers rotate 0,1,2; stage t+2
  for (int t3 = 0; t3 < 126; t3 += 3) {
    BODY(0, 2, t3 + 2);
    BODY(1, 0, t3 + 3);
    BODY(2, 1, t3 + 4);
  }
  // t = 126 (buf 0): no stage; drain tile 127's loads
  RD_AB(0);
  VMC(0);
  BAR();
  LGKM0();
  MFMA64();
  BAR();
  // t = 127 (buf 1)
  RD_AB(1);
  LGKM0();
  MFMA64();

  // epilogue: C/D layout col=lane&15, row=(lane>>4)*4+r
  const int crow = (lane >> 4) * 4;
  const int ccol = lane & 15;
  float* Cw = C + (row0 + wm * 128 + crow) * (size_t)N_DIM + col0 + wn * 128 + ccol;
#pragma unroll
  for (int m = 0; m < 8; ++m)
#pragma unroll
    for (int n = 0; n < 8; ++n)
#pragma unroll
      for (int r = 0; r < 4; ++r)
        Cw[(size_t)(m * 16 + r) * N_DIM + n * 16] = acc[m][n][r];
}

// ---------------------------------------------------------------------------
extern "C" void kernel_launch(void* const* d_in, const int* in_sizes, int n_in,
                              void* d_out, int out_size, void* d_ws, size_t ws_size,
                              hipStream_t stream) {
  const float* x = (const float*)d_in[0];
  const int* Wmag = (const int*)d_in[1];
  const int* Wsgn = (const int*)d_in[2];
  const float* scales = (const float*)d_in[3];
  const float* alphas = (const float*)d_in[4];
  const float* powers = (const float*)d_in[5];
  const float* divisors = (const float*)d_in[6];
  float* out = (float*)d_out;

  _Float16* xh = (_Float16*)d_ws;                        // 32 MB
  _Float16* Wh = xh + (size_t)M_DIM * K_DIM;             // 90 MB

  // 1) dequantize W -> fp16 [N][K]  (per-row LUT, one block per row)
  dequant_kernel<<<N_DIM, 256, 0, stream>>>(
      Wmag, Wsgn, scales, alphas, powers, divisors, Wh);
  // 2) x -> fp16 [M][K]
  {
    int nthreads_total = (M_DIM * K_DIM) / 8;
    xconv_kernel<<<nthreads_total / 256, 256, 0, stream>>>(x, xh);
  }
  // 3) GEMM: [M][K] x [N][K]^T -> [M][N] f32
  {
    dim3 grid(NBM * NBN);  // 688
    gemm_kernel<<<grid, 256, 0, stream>>>(xh, Wh, out);
  }
}

// Round 15
// 467.033 us; speedup vs baseline: 1.1214x; 1.1214x over previous
//
#include <hip/hip_runtime.h>
#include <hip/hip_bf16.h>
#include <hip/hip_fp16.h>

// Problem constants (reference: OUT=11008, IN=4096, B=2, S=2048)
#define K_DIM 4096
#define N_DIM 11008
#define M_DIM 4096  // B*S

typedef _Float16 f16x8 __attribute__((ext_vector_type(8)));
typedef float f32x4 __attribute__((ext_vector_type(4)));

typedef const __attribute__((address_space(1))) void* gas_cptr;
typedef __attribute__((address_space(3))) void* las_ptr;

__device__ __forceinline__ void gload_lds16(const void* g, void* l) {
  __builtin_amdgcn_global_load_lds((gas_cptr)g, (las_ptr)l, 16, 0, 0);
}

// ---------------------------------------------------------------------------
// Fused prep kernel: blocks [0, N_DIM) do per-row LUT dequant (r9, proven);
// blocks [N_DIM, N_DIM + M*K/8/256) do x fp32->fp16 conversion.  Both are
// memory-bound; merging removes a dispatch boundary and overlaps the dequant
// tail with xconv blocks.
// ---------------------------------------------------------------------------
#define XCONV_BLOCKS ((M_DIM * K_DIM) / 8 / 256)  // 8192

__global__ __launch_bounds__(256) void prep_kernel(
    const int* __restrict__ mag, const int* __restrict__ sgn,
    const float* __restrict__ scales, const float* __restrict__ alphas,
    const float* __restrict__ powers, const float* __restrict__ divisors,
    _Float16* __restrict__ Wh, const float* __restrict__ x,
    _Float16* __restrict__ xh) {
  const int t = threadIdx.x;
  if (blockIdx.x >= N_DIM) {
    // ---- xconv path
    int v = (blockIdx.x - N_DIM) * 256 + t;
    int base = v * 8;
    float4 a = *(const float4*)(x + base);
    float4 b = *(const float4*)(x + base + 4);
    f16x8 o;
    o[0] = (_Float16)a.x; o[1] = (_Float16)a.y;
    o[2] = (_Float16)a.z; o[3] = (_Float16)a.w;
    o[4] = (_Float16)b.x; o[5] = (_Float16)b.y;
    o[6] = (_Float16)b.z; o[7] = (_Float16)b.w;
    *(f16x8*)&xh[base] = o;
    return;
  }
  // ---- dequant path: mag in [0,255] -> 256-entry per-row curve LUT
  __shared__ float tbl[256];
  const int o = blockIdx.x;  // row
  {
    float sc = scales[o];
    float al = alphas[o];
    float p = powers[o];
    float idv = 1.0f / divisors[o];
    float xn = (float)t * idv;
    float pw = __powf(xn, p);  // t==0 -> 0
    tbl[t] = sc * (al * xn + (1.0f - al) * pw);
  }
  __syncthreads();

  const size_t base = (size_t)o * K_DIM + (size_t)t * 16;
  const int4* mp = (const int4*)(mag + base);
  const int4* sp = (const int4*)(sgn + base);
  int4 m0 = mp[0], m1 = mp[1], m2 = mp[2], m3 = mp[3];
  int4 s0 = sp[0], s1 = sp[1], s2 = sp[2], s3 = sp[3];

  int mi[16] = {m0.x, m0.y, m0.z, m0.w, m1.x, m1.y, m1.z, m1.w,
                m2.x, m2.y, m2.z, m2.w, m3.x, m3.y, m3.z, m3.w};
  int si[16] = {s0.x, s0.y, s0.z, s0.w, s1.x, s1.y, s1.z, s1.w,
                s2.x, s2.y, s2.z, s2.w, s3.x, s3.y, s3.z, s3.w};

  f16x8 oa, ob;
#pragma unroll
  for (int e = 0; e < 8; ++e) oa[e] = (_Float16)((float)si[e] * tbl[mi[e]]);
#pragma unroll
  for (int e = 0; e < 8; ++e) ob[e] = (_Float16)((float)si[8 + e] * tbl[mi[8 + e]]);
  *(f16x8*)&Wh[base] = oa;
  *(f16x8*)&Wh[base + 8] = ob;
}

// ---------------------------------------------------------------------------
// 256x256 8-phase GEMM_BT (r4 config — best measured of 9 structure variants:
// 377.9us, MfmaUtil 45.4%, bank conflicts 0).  BK=64, 512 thr = 8 waves (2x4),
// 16x16x32 f16 MFMA, per-phase staging, vmcnt(4) at ph2/ph4.
// LDS: 2 dbuf x 4 regions (A-kh0, A-kh1, B-kh0, B-kh1), 16KB each = 128 KiB.
// Swizzle (T2): logical colbyte = physical ^ (((row>>1)&3)<<4) — with 64B
// rows an 8-lane b128 phase hits all 8 four-bank groups (verified: conflict
// counter == 0).  Structure-family post-mortem (r4-r14): 6 schedule variants
// (barrier-phases / depth-3 / counted-lgkm / SGB-interleave / read-ahead /
// wave-specialization) and 3 occupancy variants all measured <= this config;
// the 44% MfmaUtil residual is LDS||MFMA serialization at 2 waves/SIMD,
// not prefetch latency (falsified), not bank conflicts (0), not occupancy
// (falsified both directions).
// ---------------------------------------------------------------------------
#define BM 256
#define BN 256
#define BK 64
#define NT (K_DIM / BK)   // 64
#define NBN (N_DIM / BN)  // 43
#define NBM (M_DIM / BM)  // 16

#define BAR() __builtin_amdgcn_s_barrier()
#define LGKM0()                                          \
  asm volatile("s_waitcnt lgkmcnt(0)" ::: "memory");     \
  __builtin_amdgcn_sched_barrier(0)
#define VMC(N) asm volatile("s_waitcnt vmcnt(" #N ")" ::: "memory")

// stage one k-half region: 2 gloads/thread (j=0: rows 0-127, j=1: rows 128-255)
#define STAGE(buf_, reg_, gbase_)                                        \
  do {                                                                   \
    gload_lds16((gbase_), &lds[buf_][reg_][wave * 512]);                 \
    gload_lds16((gbase_) + 128 * (size_t)K_DIM,                          \
                &lds[buf_][reg_][4096 + wave * 512]);                    \
  } while (0)

#define LOAD_A4(buf_, kh_, qm_)                                          \
  _Pragma("unroll") for (int m = 0; m < 4; ++m)                          \
      af[m] = *(const f16x8*)&lds[buf_][kh_][aoff + ((qm_)*4 + m) * 512];

#define LOAD_B4(buf_, kh_)                                               \
  _Pragma("unroll") for (int n = 0; n < 4; ++n)                          \
      bf[n] = *(const f16x8*)&lds[buf_][2 + (kh_)][boff + n * 512];

#define MFMA_Q(qm_)                                                      \
  do {                                                                   \
    __builtin_amdgcn_s_setprio(1);                                       \
    _Pragma("unroll") for (int i = 0; i < 4; ++i)                        \
        _Pragma("unroll") for (int j = 0; j < 4; ++j)                    \
            acc[(qm_)*4 + i][j] = __builtin_amdgcn_mfma_f32_16x16x32_f16(\
                af[i], bf[j], acc[(qm_)*4 + i][j], 0, 0, 0);             \
    __builtin_amdgcn_s_setprio(0);                                       \
  } while (0)

__global__ __launch_bounds__(512, 2) void gemm_kernel(
    const _Float16* __restrict__ A, const _Float16* __restrict__ Bt,
    float* __restrict__ C) {
  __shared__ _Float16 lds[2][4][8192];  // 128 KiB

  const int tid = threadIdx.x;
  const int lane = tid & 63;
  const int wave = tid >> 6;
  const int wm = wave >> 2;  // 0..1
  const int wn = wave & 3;   // 0..3

  // XCD-aware swizzle (T1), bn-fastest: 688 = 8 XCDs x 86
  const int bid = blockIdx.x;
  const int g = (bid & 7) * 86 + (bid >> 3);
  const int bm = g / NBN;
  const int bn = g - bm * NBN;
  const size_t row0 = (size_t)bm * BM;
  const size_t col0 = (size_t)bn * BN;

  // staging addressing (T2 pre-swizzled source)
  const int sr = tid >> 2;               // row within j=0 half
  const int pcb = (tid & 3) * 16;        // physical col byte
  const int cb = pcb ^ (((sr >> 1) & 3) << 4);  // logical col byte
  const _Float16* gA = A + (row0 + sr) * (size_t)K_DIM + cb / 2;
  const _Float16* gB = Bt + (col0 + sr) * (size_t)K_DIM + cb / 2;

  // fragment read addressing (16x16x32: row=lane&15, kgrp=lane>>4)
  const int frow = lane & 15;
  const int fpcb = 16 * ((lane >> 4) ^ ((lane >> 1) & 3));  // swizzled col byte
  const int aoff = (wm * 128 + frow) * 32 + fpcb / 2;  // + frag*512
  const int boff = (wn * 64 + frow) * 32 + fpcb / 2;   // + n*512

  f32x4 acc[8][4];
#pragma unroll
  for (int m = 0; m < 8; ++m)
#pragma unroll
    for (int n = 0; n < 4; ++n) acc[m][n] = (f32x4)0.0f;

  // prologue: stage all 4 halves of tile 0 into buf 0
  STAGE(0, 0, gA);        // A kh0
  STAGE(0, 2, gB);        // B kh0
  STAGE(0, 1, gA + 32);   // A kh1
  STAGE(0, 3, gB + 32);   // B kh1
  VMC(4);                 // A kh0 + B kh0 resident
  BAR();

  f16x8 af[4], bf[4];

  for (int t = 0; t < NT - 1; ++t) {
    const int cur = t & 1;
    const int nxt = cur ^ 1;
    const _Float16* gAn = gA + (size_t)(t + 1) * BK;
    const _Float16* gBn = gB + (size_t)(t + 1) * BK;

    // Phase 1: kh0, m-half0 | stage A-kh0(t+1)
    LOAD_A4(cur, 0, 0);
    LOAD_B4(cur, 0);
    STAGE(nxt, 0, gAn);
    BAR(); LGKM0();
    MFMA_Q(0);
    BAR();
    // Phase 2: kh0, m-half1 | stage B-kh0(t+1) | vmcnt(4): A1,B1(t) resident
    LOAD_A4(cur, 0, 1);
    STAGE(nxt, 2, gBn);
    VMC(4);
    BAR(); LGKM0();
    MFMA_Q(1);
    BAR();
    // Phase 3: kh1, m-half0 | stage A-kh1(t+1)
    LOAD_A4(cur, 1, 0);
    LOAD_B4(cur, 1);
    STAGE(nxt, 1, gAn + 32);
    BAR(); LGKM0();
    MFMA_Q(0);
    BAR();
    // Phase 4: kh1, m-half1 | stage B-kh1(t+1) | vmcnt(4): A0,B0(t+1) resident
    LOAD_A4(cur, 1, 1);
    STAGE(nxt, 3, gBn + 32);
    VMC(4);
    BAR(); LGKM0();
    MFMA_Q(1);
    BAR();
  }

  // tail: tile NT-1 in buf 1, no staging
  LOAD_A4(1, 0, 0);
  LOAD_B4(1, 0);
  BAR(); LGKM0();
  MFMA_Q(0);
  BAR();
  LOAD_A4(1, 0, 1);
  VMC(0);  // A-kh1, B-kh1 of last tile fully resident
  BAR(); LGKM0();
  MFMA_Q(1);
  BAR();
  LOAD_A4(1, 1, 0);
  LOAD_B4(1, 1);
  BAR(); LGKM0();
  MFMA_Q(0);
  BAR();
  LOAD_A4(1, 1, 1);
  LGKM0();
  MFMA_Q(1);

  // epilogue: C/D layout col=lane&15, row=(lane>>4)*4+r
  const int crow = (lane >> 4) * 4;
  const int ccol = lane & 15;
  float* Cw = C + (row0 + wm * 128 + crow) * (size_t)N_DIM + col0 + wn * 64 + ccol;
#pragma unroll
  for (int m = 0; m < 8; ++m)
#pragma unroll
    for (int n = 0; n < 4; ++n)
#pragma unroll
      for (int r = 0; r < 4; ++r)
        Cw[(size_t)(m * 16 + r) * N_DIM + n * 16] = acc[m][n][r];
}

// ---------------------------------------------------------------------------
extern "C" void kernel_launch(void* const* d_in, const int* in_sizes, int n_in,
                              void* d_out, int out_size, void* d_ws, size_t ws_size,
                              hipStream_t stream) {
  const float* x = (const float*)d_in[0];
  const int* Wmag = (const int*)d_in[1];
  const int* Wsgn = (const int*)d_in[2];
  const float* scales = (const float*)d_in[3];
  const float* alphas = (const float*)d_in[4];
  const float* powers = (const float*)d_in[5];
  const float* divisors = (const float*)d_in[6];
  float* out = (float*)d_out;

  _Float16* xh = (_Float16*)d_ws;                        // 32 MB
  _Float16* Wh = xh + (size_t)M_DIM * K_DIM;             // 90 MB

  // 1) fused prep: dequant W -> fp16 [N][K] (LUT) + x -> fp16 [M][K]
  prep_kernel<<<N_DIM + XCONV_BLOCKS, 256, 0, stream>>>(
      Wmag, Wsgn, scales, alphas, powers, divisors, Wh, x, xh);
  // 2) GEMM: [M][K] x [N][K]^T -> [M][N] f32
  {
    dim3 grid(NBM * NBN);  // 688
    gemm_kernel<<<grid, 512, 0, stream>>>(xh, Wh, out);
  }
}

// Round 16
// 466.385 us; speedup vs baseline: 1.1229x; 1.0014x over previous
//
#include <hip/hip_runtime.h>
#include <hip/hip_bf16.h>
#include <hip/hip_fp16.h>

// Problem constants (reference: OUT=11008, IN=4096, B=2, S=2048)
#define K_DIM 4096
#define N_DIM 11008
#define M_DIM 4096  // B*S

typedef _Float16 f16x8 __attribute__((ext_vector_type(8)));
typedef float f32x4 __attribute__((ext_vector_type(4)));

typedef const __attribute__((address_space(1))) void* gas_cptr;
typedef __attribute__((address_space(3))) void* las_ptr;

__device__ __forceinline__ void gload_lds16(const void* g, void* l) {
  __builtin_amdgcn_global_load_lds((gas_cptr)g, (las_ptr)l, 16, 0, 0);
}

// ---------------------------------------------------------------------------
// Fused prep kernel (r15, proven, ~HBM floor): blocks [0, N_DIM) do per-row
// LUT dequant; blocks [N_DIM, ...) do x fp32->fp16 conversion.
// ---------------------------------------------------------------------------
#define XCONV_BLOCKS ((M_DIM * K_DIM) / 8 / 256)  // 8192

__global__ __launch_bounds__(256) void prep_kernel(
    const int* __restrict__ mag, const int* __restrict__ sgn,
    const float* __restrict__ scales, const float* __restrict__ alphas,
    const float* __restrict__ powers, const float* __restrict__ divisors,
    _Float16* __restrict__ Wh, const float* __restrict__ x,
    _Float16* __restrict__ xh) {
  const int t = threadIdx.x;
  if (blockIdx.x >= N_DIM) {
    // ---- xconv path
    int v = (blockIdx.x - N_DIM) * 256 + t;
    int base = v * 8;
    float4 a = *(const float4*)(x + base);
    float4 b = *(const float4*)(x + base + 4);
    f16x8 o;
    o[0] = (_Float16)a.x; o[1] = (_Float16)a.y;
    o[2] = (_Float16)a.z; o[3] = (_Float16)a.w;
    o[4] = (_Float16)b.x; o[5] = (_Float16)b.y;
    o[6] = (_Float16)b.z; o[7] = (_Float16)b.w;
    *(f16x8*)&xh[base] = o;
    return;
  }
  // ---- dequant path: mag in [0,255] -> 256-entry per-row curve LUT
  __shared__ float tbl[256];
  const int o = blockIdx.x;  // row
  {
    float sc = scales[o];
    float al = alphas[o];
    float p = powers[o];
    float idv = 1.0f / divisors[o];
    float xn = (float)t * idv;
    float pw = __powf(xn, p);  // t==0 -> 0
    tbl[t] = sc * (al * xn + (1.0f - al) * pw);
  }
  __syncthreads();

  const size_t base = (size_t)o * K_DIM + (size_t)t * 16;
  const int4* mp = (const int4*)(mag + base);
  const int4* sp = (const int4*)(sgn + base);
  int4 m0 = mp[0], m1 = mp[1], m2 = mp[2], m3 = mp[3];
  int4 s0 = sp[0], s1 = sp[1], s2 = sp[2], s3 = sp[3];

  int mi[16] = {m0.x, m0.y, m0.z, m0.w, m1.x, m1.y, m1.z, m1.w,
                m2.x, m2.y, m2.z, m2.w, m3.x, m3.y, m3.z, m3.w};
  int si[16] = {s0.x, s0.y, s0.z, s0.w, s1.x, s1.y, s1.z, s1.w,
                s2.x, s2.y, s2.z, s2.w, s3.x, s3.y, s3.z, s3.w};

  f16x8 oa, ob;
#pragma unroll
  for (int e = 0; e < 8; ++e) oa[e] = (_Float16)((float)si[e] * tbl[mi[e]]);
#pragma unroll
  for (int e = 0; e < 8; ++e) ob[e] = (_Float16)((float)si[8 + e] * tbl[mi[8 + e]]);
  *(f16x8*)&Wh[base] = oa;
  *(f16x8*)&Wh[base + 8] = ob;
}

// ---------------------------------------------------------------------------
// 256x256 8-phase GEMM_BT — r4 config (best of 9 structure variants) MINUS
// the explicit lgkmcnt(0)+sched_barrier(0) after each barrier (r16 change).
// Rationale: ds_reads here are plain C++ loads — the compiler tracks their
// deps and emits STAGGERED lgkmcnt(4/3/1/0) before each dependent MFMA
// (m97 asm finding), letting early MFMAs issue while later reads drain.
// The old blanket lgkmcnt(0)+SBAR fence (rule #18 is for inline-asm reads
// only) forced all 8 reads to retire before the FIRST MFMA and pinned the
// schedule (m141: pinning = 874->510 TF).  Correctness: VMC asm ("memory")
// still fences LDS re-reads across buffer reuse; each MFMA's operand waits
// retire reads before the closing BAR (WAR-safe); VMC(4)+BAR still publish
// staged data cross-wave before reads.
// Swizzle (T2, 0 conflicts measured): colbyte ^= ((row>>1)&3)<<4.
// ---------------------------------------------------------------------------
#define BM 256
#define BN 256
#define BK 64
#define NT (K_DIM / BK)   // 64
#define NBN (N_DIM / BN)  // 43
#define NBM (M_DIM / BM)  // 16

#define BAR() __builtin_amdgcn_s_barrier()
#define VMC(N) asm volatile("s_waitcnt vmcnt(" #N ")" ::: "memory")

// stage one k-half region: 2 gloads/thread (j=0: rows 0-127, j=1: rows 128-255)
#define STAGE(buf_, reg_, gbase_)                                        \
  do {                                                                   \
    gload_lds16((gbase_), &lds[buf_][reg_][wave * 512]);                 \
    gload_lds16((gbase_) + 128 * (size_t)K_DIM,                          \
                &lds[buf_][reg_][4096 + wave * 512]);                    \
  } while (0)

#define LOAD_A4(buf_, kh_, qm_)                                          \
  _Pragma("unroll") for (int m = 0; m < 4; ++m)                          \
      af[m] = *(const f16x8*)&lds[buf_][kh_][aoff + ((qm_)*4 + m) * 512];

#define LOAD_B4(buf_, kh_)                                               \
  _Pragma("unroll") for (int n = 0; n < 4; ++n)                          \
      bf[n] = *(const f16x8*)&lds[buf_][2 + (kh_)][boff + n * 512];

#define MFMA_Q(qm_)                                                      \
  do {                                                                   \
    __builtin_amdgcn_s_setprio(1);                                       \
    _Pragma("unroll") for (int i = 0; i < 4; ++i)                        \
        _Pragma("unroll") for (int j = 0; j < 4; ++j)                    \
            acc[(qm_)*4 + i][j] = __builtin_amdgcn_mfma_f32_16x16x32_f16(\
                af[i], bf[j], acc[(qm_)*4 + i][j], 0, 0, 0);             \
    __builtin_amdgcn_s_setprio(0);                                       \
  } while (0)

__global__ __launch_bounds__(512, 2) void gemm_kernel(
    const _Float16* __restrict__ A, const _Float16* __restrict__ Bt,
    float* __restrict__ C) {
  __shared__ _Float16 lds[2][4][8192];  // 128 KiB

  const int tid = threadIdx.x;
  const int lane = tid & 63;
  const int wave = tid >> 6;
  const int wm = wave >> 2;  // 0..1
  const int wn = wave & 3;   // 0..3

  // XCD-aware swizzle (T1), bn-fastest: 688 = 8 XCDs x 86
  const int bid = blockIdx.x;
  const int g = (bid & 7) * 86 + (bid >> 3);
  const int bm = g / NBN;
  const int bn = g - bm * NBN;
  const size_t row0 = (size_t)bm * BM;
  const size_t col0 = (size_t)bn * BN;

  // staging addressing (T2 pre-swizzled source)
  const int sr = tid >> 2;               // row within j=0 half
  const int pcb = (tid & 3) * 16;        // physical col byte
  const int cb = pcb ^ (((sr >> 1) & 3) << 4);  // logical col byte
  const _Float16* gA = A + (row0 + sr) * (size_t)K_DIM + cb / 2;
  const _Float16* gB = Bt + (col0 + sr) * (size_t)K_DIM + cb / 2;

  // fragment read addressing (16x16x32: row=lane&15, kgrp=lane>>4)
  const int frow = lane & 15;
  const int fpcb = 16 * ((lane >> 4) ^ ((lane >> 1) & 3));  // swizzled col byte
  const int aoff = (wm * 128 + frow) * 32 + fpcb / 2;  // + frag*512
  const int boff = (wn * 64 + frow) * 32 + fpcb / 2;   // + n*512

  f32x4 acc[8][4];
#pragma unroll
  for (int m = 0; m < 8; ++m)
#pragma unroll
    for (int n = 0; n < 4; ++n) acc[m][n] = (f32x4)0.0f;

  // prologue: stage all 4 halves of tile 0 into buf 0
  STAGE(0, 0, gA);        // A kh0
  STAGE(0, 2, gB);        // B kh0
  STAGE(0, 1, gA + 32);   // A kh1
  STAGE(0, 3, gB + 32);   // B kh1
  VMC(4);                 // A kh0 + B kh0 resident
  BAR();

  f16x8 af[4], bf[4];

  for (int t = 0; t < NT - 1; ++t) {
    const int cur = t & 1;
    const int nxt = cur ^ 1;
    const _Float16* gAn = gA + (size_t)(t + 1) * BK;
    const _Float16* gBn = gB + (size_t)(t + 1) * BK;

    // Phase 1: kh0, m-half0 | stage A-kh0(t+1)
    LOAD_A4(cur, 0, 0);
    LOAD_B4(cur, 0);
    STAGE(nxt, 0, gAn);
    BAR();
    MFMA_Q(0);
    BAR();
    // Phase 2: kh0, m-half1 | stage B-kh0(t+1) | vmcnt(4): A1,B1(t) resident
    LOAD_A4(cur, 0, 1);
    STAGE(nxt, 2, gBn);
    VMC(4);
    BAR();
    MFMA_Q(1);
    BAR();
    // Phase 3: kh1, m-half0 | stage A-kh1(t+1)
    LOAD_A4(cur, 1, 0);
    LOAD_B4(cur, 1);
    STAGE(nxt, 1, gAn + 32);
    BAR();
    MFMA_Q(0);
    BAR();
    // Phase 4: kh1, m-half1 | stage B-kh1(t+1) | vmcnt(4): A0,B0(t+1) resident
    LOAD_A4(cur, 1, 1);
    STAGE(nxt, 3, gBn + 32);
    VMC(4);
    BAR();
    MFMA_Q(1);
    BAR();
  }

  // tail: tile NT-1 in buf 1, no staging
  LOAD_A4(1, 0, 0);
  LOAD_B4(1, 0);
  BAR();
  MFMA_Q(0);
  BAR();
  LOAD_A4(1, 0, 1);
  VMC(0);  // A-kh1, B-kh1 of last tile fully resident
  BAR();
  MFMA_Q(1);
  BAR();
  LOAD_A4(1, 1, 0);
  LOAD_B4(1, 1);
  BAR();
  MFMA_Q(0);
  BAR();
  LOAD_A4(1, 1, 1);
  MFMA_Q(1);

  // epilogue: C/D layout col=lane&15, row=(lane>>4)*4+r
  const int crow = (lane >> 4) * 4;
  const int ccol = lane & 15;
  float* Cw = C + (row0 + wm * 128 + crow) * (size_t)N_DIM + col0 + wn * 64 + ccol;
#pragma unroll
  for (int m = 0; m < 8; ++m)
#pragma unroll
    for (int n = 0; n < 4; ++n)
#pragma unroll
      for (int r = 0; r < 4; ++r)
        Cw[(size_t)(m * 16 + r) * N_DIM + n * 16] = acc[m][n][r];
}

// ---------------------------------------------------------------------------
extern "C" void kernel_launch(void* const* d_in, const int* in_sizes, int n_in,
                              void* d_out, int out_size, void* d_ws, size_t ws_size,
                              hipStream_t stream) {
  const float* x = (const float*)d_in[0];
  const int* Wmag = (const int*)d_in[1];
  const int* Wsgn = (const int*)d_in[2];
  const float* scales = (const float*)d_in[3];
  const float* alphas = (const float*)d_in[4];
  const float* powers = (const float*)d_in[5];
  const float* divisors = (const float*)d_in[6];
  float* out = (float*)d_out;

  _Float16* xh = (_Float16*)d_ws;                        // 32 MB
  _Float16* Wh = xh + (size_t)M_DIM * K_DIM;             // 90 MB

  // 1) fused prep: dequant W -> fp16 [N][K] (LUT) + x -> fp16 [M][K]
  prep_kernel<<<N_DIM + XCONV_BLOCKS, 256, 0, stream>>>(
      Wmag, Wsgn, scales, alphas, powers, divisors, Wh, x, xh);
  // 2) GEMM: [M][K] x [N][K]^T -> [M][N] f32
  {
    dim3 grid(NBM * NBN);  // 688
    gemm_kernel<<<grid, 512, 0, stream>>>(xh, Wh, out);
  }
}

// Round 17
// 462.941 us; speedup vs baseline: 1.1313x; 1.0074x over previous
//
#include <hip/hip_runtime.h>
#include <hip/hip_bf16.h>
#include <hip/hip_fp16.h>

// Problem constants (reference: OUT=11008, IN=4096, B=2, S=2048)
#define K_DIM 4096
#define N_DIM 11008
#define M_DIM 4096  // B*S

typedef _Float16 f16x8 __attribute__((ext_vector_type(8)));
typedef float f32x4 __attribute__((ext_vector_type(4)));

typedef const __attribute__((address_space(1))) void* gas_cptr;
typedef __attribute__((address_space(3))) void* las_ptr;

__device__ __forceinline__ void gload_lds16(const void* g, void* l) {
  __builtin_amdgcn_global_load_lds((gas_cptr)g, (las_ptr)l, 16, 0, 0);
}

// ---------------------------------------------------------------------------
// Fused prep kernel (r15, proven, ~HBM floor): blocks [0, N_DIM) do per-row
// LUT dequant; blocks [N_DIM, ...) do x fp32->fp16 conversion.
// ---------------------------------------------------------------------------
#define XCONV_BLOCKS ((M_DIM * K_DIM) / 8 / 256)  // 8192

__global__ __launch_bounds__(256) void prep_kernel(
    const int* __restrict__ mag, const int* __restrict__ sgn,
    const float* __restrict__ scales, const float* __restrict__ alphas,
    const float* __restrict__ powers, const float* __restrict__ divisors,
    _Float16* __restrict__ Wh, const float* __restrict__ x,
    _Float16* __restrict__ xh) {
  const int t = threadIdx.x;
  if (blockIdx.x >= N_DIM) {
    // ---- xconv path
    int v = (blockIdx.x - N_DIM) * 256 + t;
    int base = v * 8;
    float4 a = *(const float4*)(x + base);
    float4 b = *(const float4*)(x + base + 4);
    f16x8 o;
    o[0] = (_Float16)a.x; o[1] = (_Float16)a.y;
    o[2] = (_Float16)a.z; o[3] = (_Float16)a.w;
    o[4] = (_Float16)b.x; o[5] = (_Float16)b.y;
    o[6] = (_Float16)b.z; o[7] = (_Float16)b.w;
    *(f16x8*)&xh[base] = o;
    return;
  }
  // ---- dequant path: mag in [0,255] -> 256-entry per-row curve LUT
  __shared__ float tbl[256];
  const int o = blockIdx.x;  // row
  {
    float sc = scales[o];
    float al = alphas[o];
    float p = powers[o];
    float idv = 1.0f / divisors[o];
    float xn = (float)t * idv;
    float pw = __powf(xn, p);  // t==0 -> 0
    tbl[t] = sc * (al * xn + (1.0f - al) * pw);
  }
  __syncthreads();

  const size_t base = (size_t)o * K_DIM + (size_t)t * 16;
  const int4* mp = (const int4*)(mag + base);
  const int4* sp = (const int4*)(sgn + base);
  int4 m0 = mp[0], m1 = mp[1], m2 = mp[2], m3 = mp[3];
  int4 s0 = sp[0], s1 = sp[1], s2 = sp[2], s3 = sp[3];

  int mi[16] = {m0.x, m0.y, m0.z, m0.w, m1.x, m1.y, m1.z, m1.w,
                m2.x, m2.y, m2.z, m2.w, m3.x, m3.y, m3.z, m3.w};
  int si[16] = {s0.x, s0.y, s0.z, s0.w, s1.x, s1.y, s1.z, s1.w,
                s2.x, s2.y, s2.z, s2.w, s3.x, s3.y, s3.z, s3.w};

  f16x8 oa, ob;
#pragma unroll
  for (int e = 0; e < 8; ++e) oa[e] = (_Float16)((float)si[e] * tbl[mi[e]]);
#pragma unroll
  for (int e = 0; e < 8; ++e) ob[e] = (_Float16)((float)si[8 + e] * tbl[mi[8 + e]]);
  *(f16x8*)&Wh[base] = oa;
  *(f16x8*)&Wh[base + 8] = ob;
}

// ---------------------------------------------------------------------------
// 256x256 8-phase GEMM_BT — r16 base with SINGLE-WAIT-PER-TILE vmcnt (r17).
// m201-style 6-phase consume lag: iter t stages A1(t+1)@ph1, B1(t+1)@ph2,
// A0(t+2)@ph3 [into CUR buf], B0(t+2)@ph4 [CUR], then one VMC(4).
// Ledger: at ph4, outstanding = A0B0(t+1)[4 leftover] + 8 this-iter = 12;
// drain-to-4 retires A0,B0(t+1) AND A1,B1(t+1) (everything iter t+1 reads),
// leaves A0,B0(t+2) in flight -> never drains to 0 mid-loop, ONE wait/tile
// (r4 had two).  WAR on cur-buf stages: regions 0/2's last ds_reads were
// consumed by the MFMA before the preceding barrier; empty asm memory fence
// pins the gload issue after that barrier.  Budgets: newest drained load
// issued >=2 phases (~1300cy) before its wait.
// Swizzle (T2, 0 conflicts measured r4-r16): colbyte ^= ((row>>1)&3)<<4.
// ---------------------------------------------------------------------------
#define BM 256
#define BN 256
#define BK 64
#define NT (K_DIM / BK)   // 64
#define NBN (N_DIM / BN)  // 43
#define NBM (M_DIM / BM)  // 16

#define BAR() __builtin_amdgcn_s_barrier()
#define VMC(N) asm volatile("s_waitcnt vmcnt(" #N ")" ::: "memory")
#define MEMFENCE() asm volatile("" ::: "memory")

// stage one k-half region: 2 gloads/thread (j=0: rows 0-127, j=1: rows 128-255)
#define STAGE(buf_, reg_, gbase_)                                        \
  do {                                                                   \
    gload_lds16((gbase_), &lds[buf_][reg_][wave * 512]);                 \
    gload_lds16((gbase_) + 128 * (size_t)K_DIM,                          \
                &lds[buf_][reg_][4096 + wave * 512]);                    \
  } while (0)

#define LOAD_A4(buf_, kh_, qm_)                                          \
  _Pragma("unroll") for (int m = 0; m < 4; ++m)                          \
      af[m] = *(const f16x8*)&lds[buf_][kh_][aoff + ((qm_)*4 + m) * 512];

#define LOAD_B4(buf_, kh_)                                               \
  _Pragma("unroll") for (int n = 0; n < 4; ++n)                          \
      bf[n] = *(const f16x8*)&lds[buf_][2 + (kh_)][boff + n * 512];

#define MFMA_Q(qm_)                                                      \
  do {                                                                   \
    __builtin_amdgcn_s_setprio(1);                                       \
    _Pragma("unroll") for (int i = 0; i < 4; ++i)                        \
        _Pragma("unroll") for (int j = 0; j < 4; ++j)                    \
            acc[(qm_)*4 + i][j] = __builtin_amdgcn_mfma_f32_16x16x32_f16(\
                af[i], bf[j], acc[(qm_)*4 + i][j], 0, 0, 0);             \
    __builtin_amdgcn_s_setprio(0);                                       \
  } while (0)

__global__ __launch_bounds__(512, 2) void gemm_kernel(
    const _Float16* __restrict__ A, const _Float16* __restrict__ Bt,
    float* __restrict__ C) {
  __shared__ _Float16 lds[2][4][8192];  // 128 KiB; regions: 0=Akh0 1=Akh1 2=Bkh0 3=Bkh1

  const int tid = threadIdx.x;
  const int lane = tid & 63;
  const int wave = tid >> 6;
  const int wm = wave >> 2;  // 0..1
  const int wn = wave & 3;   // 0..3

  // XCD-aware swizzle (T1), bn-fastest: 688 = 8 XCDs x 86
  const int bid = blockIdx.x;
  const int g = (bid & 7) * 86 + (bid >> 3);
  const int bm = g / NBN;
  const int bn = g - bm * NBN;
  const size_t row0 = (size_t)bm * BM;
  const size_t col0 = (size_t)bn * BN;

  // staging addressing (T2 pre-swizzled source)
  const int sr = tid >> 2;               // row within j=0 half
  const int pcb = (tid & 3) * 16;        // physical col byte
  const int cb = pcb ^ (((sr >> 1) & 3) << 4);  // logical col byte
  const _Float16* gA = A + (row0 + sr) * (size_t)K_DIM + cb / 2;
  const _Float16* gB = Bt + (col0 + sr) * (size_t)K_DIM + cb / 2;

  // fragment read addressing (16x16x32: row=lane&15, kgrp=lane>>4)
  const int frow = lane & 15;
  const int fpcb = 16 * ((lane >> 4) ^ ((lane >> 1) & 3));  // swizzled col byte
  const int aoff = (wm * 128 + frow) * 32 + fpcb / 2;  // + frag*512
  const int boff = (wn * 64 + frow) * 32 + fpcb / 2;   // + n*512

  f32x4 acc[8][4];
#pragma unroll
  for (int m = 0; m < 8; ++m)
#pragma unroll
    for (int n = 0; n < 4; ++n) acc[m][n] = (f32x4)0.0f;

  // prologue: stage tile 0 (all 4 regions) + A0,B0 of tile 1
  STAGE(0, 0, gA);        // A kh0 (t0)
  STAGE(0, 2, gB);        // B kh0 (t0)
  STAGE(0, 1, gA + 32);   // A kh1 (t0)
  STAGE(0, 3, gB + 32);   // B kh1 (t0)
  STAGE(1, 0, gA + BK);   // A kh0 (t1)
  STAGE(1, 2, gB + BK);   // B kh0 (t1)
  VMC(4);                 // drains the 8 loads of tile 0; t1's 4 stay in flight
  BAR();

  f16x8 af[4], bf[4];

  // main loop: t = 0 .. NT-3 (stages reach t+2 = NT-1 max)
  for (int t = 0; t <= NT - 3; ++t) {
    const int cur = t & 1;
    const int nxt = cur ^ 1;
    const _Float16* gAn = gA + (size_t)(t + 1) * BK;
    const _Float16* gBn = gB + (size_t)(t + 1) * BK;
    const _Float16* gA2 = gA + (size_t)(t + 2) * BK;
    const _Float16* gB2 = gB + (size_t)(t + 2) * BK;

    // Phase 1: kh0, m-half0 | stage A-kh1(t+1) -> nxt
    LOAD_A4(cur, 0, 0);
    LOAD_B4(cur, 0);
    STAGE(nxt, 1, gAn + 32);
    BAR();
    MFMA_Q(0);
    BAR();
    // Phase 2: kh0, m-half1 | stage B-kh1(t+1) -> nxt
    LOAD_A4(cur, 0, 1);
    STAGE(nxt, 3, gBn + 32);
    BAR();
    MFMA_Q(1);
    BAR();
    // Phase 3: kh1, m-half0 | stage A-kh0(t+2) -> CUR (reg 0: last read ph2,
    // retired before ph2's closing BAR; fence pins issue after that BAR)
    LOAD_A4(cur, 1, 0);
    LOAD_B4(cur, 1);
    MEMFENCE();
    STAGE(cur, 0, gA2);
    BAR();
    MFMA_Q(0);
    BAR();
    // Phase 4: kh1, m-half1 | stage B-kh0(t+2) -> CUR | single VMC(4)/tile
    LOAD_A4(cur, 1, 1);
    MEMFENCE();
    STAGE(cur, 2, gB2);
    VMC(4);
    BAR();
    MFMA_Q(1);
    BAR();
  }

  // ---- tail iter t = NT-2 (cur = (NT-2)&1 = 0, nxt = 1): stage only
  // A1,B1(NT-1); VMC(0) drains them + leftover A0,B0(NT-1).
  {
    const _Float16* gAn = gA + (size_t)(NT - 1) * BK;
    const _Float16* gBn = gB + (size_t)(NT - 1) * BK;
    LOAD_A4(0, 0, 0);
    LOAD_B4(0, 0);
    STAGE(1, 1, gAn + 32);
    BAR();
    MFMA_Q(0);
    BAR();
    LOAD_A4(0, 0, 1);
    STAGE(1, 3, gBn + 32);
    BAR();
    MFMA_Q(1);
    BAR();
    LOAD_A4(0, 1, 0);
    LOAD_B4(0, 1);
    BAR();
    MFMA_Q(0);
    BAR();
    LOAD_A4(0, 1, 1);
    VMC(0);
    BAR();
    MFMA_Q(1);
    BAR();
  }
  // ---- final tile NT-1 (buf 1): all resident, no stages, no waits
  LOAD_A4(1, 0, 0);
  LOAD_B4(1, 0);
  BAR();
  MFMA_Q(0);
  BAR();
  LOAD_A4(1, 0, 1);
  BAR();
  MFMA_Q(1);
  BAR();
  LOAD_A4(1, 1, 0);
  LOAD_B4(1, 1);
  BAR();
  MFMA_Q(0);
  BAR();
  LOAD_A4(1, 1, 1);
  MFMA_Q(1);

  // epilogue: C/D layout col=lane&15, row=(lane>>4)*4+r
  const int crow = (lane >> 4) * 4;
  const int ccol = lane & 15;
  float* Cw = C + (row0 + wm * 128 + crow) * (size_t)N_DIM + col0 + wn * 64 + ccol;
#pragma unroll
  for (int m = 0; m < 8; ++m)
#pragma unroll
    for (int n = 0; n < 4; ++n)
#pragma unroll
      for (int r = 0; r < 4; ++r)
        Cw[(size_t)(m * 16 + r) * N_DIM + n * 16] = acc[m][n][r];
}

// ---------------------------------------------------------------------------
extern "C" void kernel_launch(void* const* d_in, const int* in_sizes, int n_in,
                              void* d_out, int out_size, void* d_ws, size_t ws_size,
                              hipStream_t stream) {
  const float* x = (const float*)d_in[0];
  const int* Wmag = (const int*)d_in[1];
  const int* Wsgn = (const int*)d_in[2];
  const float* scales = (const float*)d_in[3];
  const float* alphas = (const float*)d_in[4];
  const float* powers = (const float*)d_in[5];
  const float* divisors = (const float*)d_in[6];
  float* out = (float*)d_out;

  _Float16* xh = (_Float16*)d_ws;                        // 32 MB
  _Float16* Wh = xh + (size_t)M_DIM * K_DIM;             // 90 MB

  // 1) fused prep: dequant W -> fp16 [N][K] (LUT) + x -> fp16 [M][K]
  prep_kernel<<<N_DIM + XCONV_BLOCKS, 256, 0, stream>>>(
      Wmag, Wsgn, scales, alphas, powers, divisors, Wh, x, xh);
  // 2) GEMM: [M][K] x [N][K]^T -> [M][N] f32
  {
    dim3 grid(NBM * NBN);  // 688
    gemm_kernel<<<grid, 512, 0, stream>>>(xh, Wh, out);
  }
}